// Round 1
// baseline (928.964 us; speedup 1.0000x reference)
//
#include <hip/hip_runtime.h>

#define DECAY_F 0.8f
#define OMD_F   0.2f
#define EPS_F   1e-5f

#define NROWS 16384
#define CBOOK 8192
#define DIM   256

// ---- ws layout (bytes) ----
// keys   : [0,      131072)  u64 per row (packed score|idx), init 0xFF
// enorm  : [131072, 163840)  float per code
// counts : [163840, 196608)  float per code, init 0
// total  : [196608, 196612)  float scalar, init 0
#define WS_KEYS   0
#define WS_ENORM  131072
#define WS_COUNTS 163840
#define WS_TOTAL  196608

// ---- d_out layout (floats) ----
// quantize        [0,        4194304)
// embed_ind       [4194304,  4210688)
// embed_norm      [4210688,  6307840)
// cluster_size_new[6307840,  6316032)
// embed_avg_new   [6316032,  8413184)
#define O_QUANT 0
#define O_IND   4194304
#define O_NORM  4210688
#define O_CSN   6307840
#define O_AVG   6316032

__device__ __forceinline__ unsigned int fkey(float f) {
    unsigned int b = __float_as_uint(f);
    return (b & 0x80000000u) ? ~b : (b | 0x80000000u);
}

// ---------- e_norm: one wave per code row (64 lanes x float4 = 256 floats) ----------
__global__ __launch_bounds__(256) void enorm_kernel(const float* __restrict__ embed,
                                                    float* __restrict__ enorm) {
    int row  = (blockIdx.x * 256 + threadIdx.x) >> 6;
    int lane = threadIdx.x & 63;
    float4 v = *(const float4*)&embed[row * DIM + lane * 4];
    float s = v.x * v.x + v.y * v.y + v.z * v.z + v.w * v.w;
    for (int m = 32; m >= 1; m >>= 1) s += __shfl_xor(s, m, 64);
    if (lane == 0) enorm[row] = s;
}

// ---------- init embed_avg_new = 0.8*embed_avg (atomic 0.2*x added later) ----------
__global__ __launch_bounds__(256) void init_avg_kernel(const float* __restrict__ embed_avg,
                                                       float* __restrict__ avg_out) {
    int i = blockIdx.x * 256 + threadIdx.x;   // float4 index, 524288 total
    float4 v = ((const float4*)embed_avg)[i];
    v.x *= DECAY_F; v.y *= DECAY_F; v.z *= DECAY_F; v.w *= DECAY_F;
    ((float4*)avg_out)[i] = v;
}

// ---------- main: fused GEMM + argmin ----------
// block = 256 threads (ty=tid/32 in [0,8) -> 8 rows each; tx=tid%32 -> 2x4 codes)
// BM=64 rows, BN=256 codes per chunk, KB=16
#define BM 64
#define BN 256
#define KB 16
#define NSPLIT 4

__global__ __launch_bounds__(256) void argmin_kernel(const float* __restrict__ x,
                                                     const float* __restrict__ embed,
                                                     const float* __restrict__ enorm,
                                                     unsigned long long* __restrict__ keys) {
    __shared__ float xs[KB][BM];   // 4 KB
    __shared__ float es[KB][BN];   // 16 KB

    const int tid = threadIdx.x;
    const int tx = tid & 31;
    const int ty = tid >> 5;
    const int rowBase = blockIdx.x * BM;
    const int cStart = blockIdx.y * (CBOOK / NSPLIT);

    float bestS[8];
    int   bestC[8];
#pragma unroll
    for (int i = 0; i < 8; i++) { bestS[i] = 3.4e38f; bestC[i] = 0; }

    float acc[8][8];

    for (int cb = 0; cb < CBOOK / NSPLIT; cb += BN) {
        const int cbase = cStart + cb;
#pragma unroll
        for (int i = 0; i < 8; i++)
#pragma unroll
            for (int j = 0; j < 8; j++) acc[i][j] = 0.f;

        for (int kk = 0; kk < DIM; kk += KB) {
            __syncthreads();
            // stage x tile (64 rows x 16 k): one float4 per thread, transposed store
            {
                int r  = tid >> 2;
                int k4 = (tid & 3) * 4;
                float4 v = *(const float4*)&x[(rowBase + r) * DIM + kk + k4];
                xs[k4 + 0][r] = v.x; xs[k4 + 1][r] = v.y;
                xs[k4 + 2][r] = v.z; xs[k4 + 3][r] = v.w;
            }
            // stage e tile (256 rows x 16 k): 4 float4 per thread, transposed store
            {
                const float4* src = (const float4*)&embed[(cbase + tid) * DIM + kk];
#pragma unroll
                for (int q = 0; q < 4; q++) {
                    float4 v = src[q];
                    es[q * 4 + 0][tid] = v.x; es[q * 4 + 1][tid] = v.y;
                    es[q * 4 + 2][tid] = v.z; es[q * 4 + 3][tid] = v.w;
                }
            }
            __syncthreads();
#pragma unroll
            for (int k = 0; k < KB; k++) {
                float xr[8], er[8];
                *(float4*)&xr[0] = *(const float4*)&xs[k][ty * 8];
                *(float4*)&xr[4] = *(const float4*)&xs[k][ty * 8 + 4];
                *(float4*)&er[0] = *(const float4*)&es[k][tx * 4];
                *(float4*)&er[4] = *(const float4*)&es[k][128 + tx * 4];
#pragma unroll
                for (int i = 0; i < 8; i++)
#pragma unroll
                    for (int j = 0; j < 8; j++)
                        acc[i][j] = fmaf(xr[i], er[j], acc[i][j]);
            }
        }
        // score = ||e||^2 - 2 x.e ; track running argmin (ascending c -> strict <)
#pragma unroll
        for (int j = 0; j < 8; j++) {
            int c = cbase + ((j < 4) ? (tx * 4 + j) : (128 + tx * 4 + (j - 4)));
            float en = enorm[c];
#pragma unroll
            for (int i = 0; i < 8; i++) {
                float s = en - 2.f * acc[i][j];
                if (s < bestS[i]) { bestS[i] = s; bestC[i] = c; }
            }
        }
    }

    // reduce across the 32 tx lanes (xor masks < 32 stay within each half-wave)
#pragma unroll
    for (int i = 0; i < 8; i++) {
        unsigned long long key =
            ((unsigned long long)fkey(bestS[i]) << 32) | (unsigned int)bestC[i];
        for (int m = 16; m >= 1; m >>= 1) {
            unsigned long long o = __shfl_xor(key, m, 64);
            if (o < key) key = o;
        }
        if (tx == 0) atomicMin(&keys[rowBase + ty * 8 + i], key);
    }
}

// ---------- scatter: quantize gather, ind write, counts, 0.2*x into avg ----------
__global__ __launch_bounds__(256) void scatter_kernel(const float* __restrict__ x,
                                                      const float* __restrict__ embed,
                                                      const unsigned long long* __restrict__ keys,
                                                      float* __restrict__ quant,
                                                      float* __restrict__ ind_out,
                                                      float* __restrict__ counts,
                                                      float* __restrict__ avg_out) {
    int i = blockIdx.x * 256 + threadIdx.x;       // float4 index over 16384*64
    int row = i >> 6;
    int c4  = (i & 63) * 4;
    int idx = (int)(keys[row] & 0xFFFFFFFFull);
    float4 e = *(const float4*)&embed[idx * DIM + c4];
    *(float4*)&quant[row * DIM + c4] = e;
    float4 xv = *(const float4*)&x[row * DIM + c4];
    atomicAdd(&avg_out[idx * DIM + c4 + 0], OMD_F * xv.x);
    atomicAdd(&avg_out[idx * DIM + c4 + 1], OMD_F * xv.y);
    atomicAdd(&avg_out[idx * DIM + c4 + 2], OMD_F * xv.z);
    atomicAdd(&avg_out[idx * DIM + c4 + 3], OMD_F * xv.w);
    if ((i & 63) == 0) {
        ind_out[row] = (float)idx;
        atomicAdd(&counts[idx], 1.0f);
    }
}

// ---------- cluster_size_new + total sum ----------
__global__ __launch_bounds__(256) void csn_kernel(const float* __restrict__ cluster_size,
                                                  const float* __restrict__ counts,
                                                  float* __restrict__ csn_out,
                                                  float* __restrict__ total) {
    int c = blockIdx.x * 256 + threadIdx.x;
    float v = DECAY_F * cluster_size[c] + OMD_F * counts[c];
    csn_out[c] = v;
    float s = v;
    for (int m = 32; m >= 1; m >>= 1) s += __shfl_xor(s, m, 64);
    __shared__ float ws4[4];
    if ((threadIdx.x & 63) == 0) ws4[threadIdx.x >> 6] = s;
    __syncthreads();
    if (threadIdx.x == 0) atomicAdd(total, ws4[0] + ws4[1] + ws4[2] + ws4[3]);
}

// ---------- embed_normalized = avg_new / cs ----------
__global__ __launch_bounds__(256) void norm_kernel(const float* __restrict__ avg_new,
                                                   const float* __restrict__ csn,
                                                   const float* __restrict__ total,
                                                   float* __restrict__ out) {
    int i = blockIdx.x * 256 + threadIdx.x;   // float4 index, 524288
    int c = i >> 6;
    float tot = *total;
    float smoothed = (csn[c] + EPS_F) / (tot + (float)CBOOK * EPS_F);
    float cs = smoothed * tot;
    float4 v = ((const float4*)avg_new)[i];
    v.x = v.x / cs; v.y = v.y / cs; v.z = v.z / cs; v.w = v.w / cs;
    ((float4*)out)[i] = v;
}

extern "C" void kernel_launch(void* const* d_in, const int* in_sizes, int n_in,
                              void* d_out, int out_size, void* d_ws, size_t ws_size,
                              hipStream_t stream) {
    const float* x            = (const float*)d_in[0];
    const float* embed        = (const float*)d_in[1];
    const float* cluster_size = (const float*)d_in[2];
    const float* embed_avg    = (const float*)d_in[3];
    float* out = (float*)d_out;
    char*  ws  = (char*)d_ws;

    unsigned long long* keys = (unsigned long long*)(ws + WS_KEYS);
    float* enorm  = (float*)(ws + WS_ENORM);
    float* counts = (float*)(ws + WS_COUNTS);
    float* total  = (float*)(ws + WS_TOTAL);

    // init workspace (must be done every call; harness does not re-poison)
    hipMemsetAsync(ws + WS_KEYS, 0xFF, NROWS * 8, stream);
    hipMemsetAsync(ws + WS_COUNTS, 0, CBOOK * 4 + 4, stream);

    enorm_kernel<<<CBOOK / 4, 256, 0, stream>>>(embed, enorm);
    init_avg_kernel<<<(CBOOK * DIM / 4) / 256, 256, 0, stream>>>(embed_avg, out + O_AVG);

    dim3 grid(NROWS / BM, NSPLIT);
    argmin_kernel<<<grid, 256, 0, stream>>>(x, embed, enorm, keys);

    scatter_kernel<<<(NROWS * DIM / 4) / 256, 256, 0, stream>>>(
        x, embed, keys, out + O_QUANT, out + O_IND, counts, out + O_AVG);

    csn_kernel<<<CBOOK / 256, 256, 0, stream>>>(cluster_size, counts, out + O_CSN, total);

    norm_kernel<<<(CBOOK * DIM / 4) / 256, 256, 0, stream>>>(
        out + O_AVG, out + O_CSN, total, out + O_NORM);
}

// Round 2
// 454.405 us; speedup vs baseline: 2.0444x; 2.0444x over previous
//
#include <hip/hip_runtime.h>
#include <hip/hip_bf16.h>

#define DECAY_F 0.8f
#define OMD_F   0.2f
#define EPS_F   1e-5f

#define NROWS 16384
#define CBOOK 8192
#define DIM   256
#define KSPLIT 768   // [hi | lo | hi] x [hi | hi | lo]

// ---- ws layout (bytes) ----
#define WS_KEYS   0u            // 16384 * 8
#define WS_ENORM  131072u       // 8192 * 4
#define WS_COUNTS 163840u       // 8192 * 4
#define WS_TOTAL  196608u       // 4
#define WS_XSPLIT 262144u       // 16384*768*2 = 25165824
#define WS_ESPLIT 25428008u     // actually computed below
#define WS_ESPLIT_OFF (262144u + 25165824u)          // 25427968
#define WS_NEED   (WS_ESPLIT_OFF + 12582912u)        // 38010880

// ---- d_out layout (floats) ----
#define O_QUANT 0
#define O_IND   4194304
#define O_NORM  4210688
#define O_CSN   6307840
#define O_AVG   6316032

typedef __attribute__((ext_vector_type(8))) short short8;
typedef __attribute__((ext_vector_type(4))) float f32x4;
typedef __attribute__((ext_vector_type(4))) unsigned short us4;

__device__ __forceinline__ unsigned int fkey(float f) {
    unsigned int b = __float_as_uint(f);
    return (b & 0x80000000u) ? ~b : (b | 0x80000000u);
}
__device__ __forceinline__ unsigned short f2bf(float f) {
    unsigned int u = __float_as_uint(f);
    unsigned int r = (u + 0x7FFFu + ((u >> 16) & 1u)) >> 16;
    return (unsigned short)r;
}
__device__ __forceinline__ float bf2f(unsigned short h) {
    return __uint_as_float(((unsigned int)h) << 16);
}

#define GLOAD_LDS16(g, l) \
    __builtin_amdgcn_global_load_lds((const __attribute__((address_space(1))) void*)(g), \
                                     (__attribute__((address_space(3))) void*)(l), 16, 0, 0)

// ---------- e_norm (fp32, exact) ----------
__global__ __launch_bounds__(256) void enorm_kernel(const float* __restrict__ embed,
                                                    float* __restrict__ enorm) {
    int row  = (blockIdx.x * 256 + threadIdx.x) >> 6;
    int lane = threadIdx.x & 63;
    float4 v = *(const float4*)&embed[row * DIM + lane * 4];
    float s = v.x * v.x + v.y * v.y + v.z * v.z + v.w * v.w;
    for (int m = 32; m >= 1; m >>= 1) s += __shfl_xor(s, m, 64);
    if (lane == 0) enorm[row] = s;
}

// ---------- init embed_avg_new = 0.8*embed_avg ----------
__global__ __launch_bounds__(256) void init_avg_kernel(const float* __restrict__ embed_avg,
                                                       float* __restrict__ avg_out) {
    int i = blockIdx.x * 256 + threadIdx.x;
    float4 v = ((const float4*)embed_avg)[i];
    v.x *= DECAY_F; v.y *= DECAY_F; v.z *= DECAY_F; v.w *= DECAY_F;
    ((float4*)avg_out)[i] = v;
}

// ---------- bf16 split: pat=0 -> [hi,lo,hi] (x);  pat=1 -> [hi,hi,lo] (e) ----------
__global__ __launch_bounds__(256) void split_kernel(const float* __restrict__ src,
                                                    unsigned short* __restrict__ dst,
                                                    int pat) {
    int i = blockIdx.x * 256 + threadIdx.x;      // float4 index
    int e4  = i * 4;
    int row = e4 >> 8;
    int k   = e4 & 255;
    float4 v = ((const float4*)src)[i];
    us4 hi, lo;
    hi.x = f2bf(v.x); lo.x = f2bf(v.x - bf2f(hi.x));
    hi.y = f2bf(v.y); lo.y = f2bf(v.y - bf2f(hi.y));
    hi.z = f2bf(v.z); lo.z = f2bf(v.z - bf2f(hi.z));
    hi.w = f2bf(v.w); lo.w = f2bf(v.w - bf2f(hi.w));
    unsigned short* base = dst + (size_t)row * KSPLIT + k;
    *(us4*)(base + 0)   = hi;
    if (pat == 0) {
        *(us4*)(base + 256) = lo;
        *(us4*)(base + 512) = hi;
    } else {
        *(us4*)(base + 256) = hi;
        *(us4*)(base + 512) = lo;
    }
}

// ---------- fused bf16 MFMA GEMM (K=768) + per-row argmin ----------
// 128x128 tile, 4 waves (2x2), each wave 64x64 = 4x4 frags of 16x16x32.
__global__ __launch_bounds__(256) void mfma_argmin_kernel(const unsigned short* __restrict__ A,
                                                          const unsigned short* __restrict__ B,
                                                          const float* __restrict__ enorm,
                                                          unsigned long long* __restrict__ keys) {
    __shared__ __align__(16) unsigned short Al[128 * 32];
    __shared__ __align__(16) unsigned short Bl[128 * 32];

    const int tid  = threadIdx.x;
    const int lane = tid & 63;
    const int wid  = tid >> 6;
    const int wr = wid >> 1, wc = wid & 1;
    const int mBase = blockIdx.y * 128;
    const int nBase = blockIdx.x * 128;

    const int lr = lane & 15;          // A-row / B-col within frag
    const int lk = (lane >> 4) * 8;    // k offset within frag

    f32x4 acc[4][4];
#pragma unroll
    for (int i = 0; i < 4; i++)
#pragma unroll
        for (int n = 0; n < 4; n++) acc[i][n] = (f32x4)0.f;

    // staging: thread t of call q covers tile bytes (t+q*256)*16
    const int r0  = tid >> 2;
    const int ck0 = (tid & 3) * 8;
    const unsigned short* srcA0 = A + (size_t)(mBase + r0) * KSPLIT + ck0;
    const unsigned short* srcA1 = srcA0 + (size_t)64 * KSPLIT;
    const unsigned short* srcB0 = B + (size_t)(nBase + r0) * KSPLIT + ck0;
    const unsigned short* srcB1 = srcB0 + (size_t)64 * KSPLIT;
    unsigned short* dstA0 = Al + tid * 8;
    unsigned short* dstA1 = Al + (tid + 256) * 8;
    unsigned short* dstB0 = Bl + tid * 8;
    unsigned short* dstB1 = Bl + (tid + 256) * 8;

    for (int kk = 0; kk < KSPLIT; kk += 32) {
        __syncthreads();   // previous compute done before overwrite
        GLOAD_LDS16(srcA0 + kk, dstA0);
        GLOAD_LDS16(srcA1 + kk, dstA1);
        GLOAD_LDS16(srcB0 + kk, dstB0);
        GLOAD_LDS16(srcB1 + kk, dstB1);
        __syncthreads();   // drains vmcnt -> tiles visible

        short8 af[4], bf[4];
#pragma unroll
        for (int i = 0; i < 4; i++)
            af[i] = *(const short8*)&Al[(wr * 64 + i * 16 + lr) * 32 + lk];
#pragma unroll
        for (int n = 0; n < 4; n++)
            bf[n] = *(const short8*)&Bl[(wc * 64 + n * 16 + lr) * 32 + lk];
#pragma unroll
        for (int i = 0; i < 4; i++)
#pragma unroll
            for (int n = 0; n < 4; n++)
                acc[i][n] = __builtin_amdgcn_mfma_f32_16x16x32_bf16(af[i], bf[n], acc[i][n], 0, 0, 0);
    }

    // epilogue: score = ||e||^2 - 2*dot; argmin per row
    float en4[4];
    int   c4[4];
#pragma unroll
    for (int n = 0; n < 4; n++) {
        c4[n]  = nBase + wc * 64 + n * 16 + lr;
        en4[n] = enorm[c4[n]];
    }
#pragma unroll
    for (int i = 0; i < 4; i++) {
#pragma unroll
        for (int reg = 0; reg < 4; reg++) {
            float bs = 3.4e38f; int bc = 0;
#pragma unroll
            for (int n = 0; n < 4; n++) {
                float s = en4[n] - 2.f * acc[i][n][reg];
                // ascending c4[n] within lane; cross-lane tie broken by key packing
                if (s < bs || (s == bs && c4[n] < bc)) { bs = s; bc = c4[n]; }
            }
            unsigned long long key =
                ((unsigned long long)fkey(bs) << 32) | (unsigned int)bc;
#pragma unroll
            for (int m = 8; m >= 1; m >>= 1) {
                unsigned long long o = __shfl_xor(key, m, 64);
                if (o < key) key = o;
            }
            if (lr == 0)
                atomicMin(&keys[mBase + wr * 64 + i * 16 + (lane >> 4) * 4 + reg], key);
        }
    }
}

// ---------- fallback fp32 fused GEMM+argmin (unchanged from R0) ----------
#define BM 64
#define BN 256
#define KB 16
#define NSPLIT 4

__global__ __launch_bounds__(256) void argmin_kernel(const float* __restrict__ x,
                                                     const float* __restrict__ embed,
                                                     const float* __restrict__ enorm,
                                                     unsigned long long* __restrict__ keys) {
    __shared__ float xs[KB][BM];
    __shared__ float es[KB][BN];

    const int tid = threadIdx.x;
    const int tx = tid & 31;
    const int ty = tid >> 5;
    const int rowBase = blockIdx.x * BM;
    const int cStart = blockIdx.y * (CBOOK / NSPLIT);

    float bestS[8];
    int   bestC[8];
#pragma unroll
    for (int i = 0; i < 8; i++) { bestS[i] = 3.4e38f; bestC[i] = 0; }

    float acc[8][8];

    for (int cb = 0; cb < CBOOK / NSPLIT; cb += BN) {
        const int cbase = cStart + cb;
#pragma unroll
        for (int i = 0; i < 8; i++)
#pragma unroll
            for (int j = 0; j < 8; j++) acc[i][j] = 0.f;

        for (int kk = 0; kk < DIM; kk += KB) {
            __syncthreads();
            {
                int r  = tid >> 2;
                int k4 = (tid & 3) * 4;
                float4 v = *(const float4*)&x[(rowBase + r) * DIM + kk + k4];
                xs[k4 + 0][r] = v.x; xs[k4 + 1][r] = v.y;
                xs[k4 + 2][r] = v.z; xs[k4 + 3][r] = v.w;
            }
            {
                const float4* src = (const float4*)&embed[(cbase + tid) * DIM + kk];
#pragma unroll
                for (int q = 0; q < 4; q++) {
                    float4 v = src[q];
                    es[q * 4 + 0][tid] = v.x; es[q * 4 + 1][tid] = v.y;
                    es[q * 4 + 2][tid] = v.z; es[q * 4 + 3][tid] = v.w;
                }
            }
            __syncthreads();
#pragma unroll
            for (int k = 0; k < KB; k++) {
                float xr[8], er[8];
                *(float4*)&xr[0] = *(const float4*)&xs[k][ty * 8];
                *(float4*)&xr[4] = *(const float4*)&xs[k][ty * 8 + 4];
                *(float4*)&er[0] = *(const float4*)&es[k][tx * 4];
                *(float4*)&er[4] = *(const float4*)&es[k][128 + tx * 4];
#pragma unroll
                for (int i = 0; i < 8; i++)
#pragma unroll
                    for (int j = 0; j < 8; j++)
                        acc[i][j] = fmaf(xr[i], er[j], acc[i][j]);
            }
        }
#pragma unroll
        for (int j = 0; j < 8; j++) {
            int c = cbase + ((j < 4) ? (tx * 4 + j) : (128 + tx * 4 + (j - 4)));
            float en = enorm[c];
#pragma unroll
            for (int i = 0; i < 8; i++) {
                float s = en - 2.f * acc[i][j];
                if (s < bestS[i]) { bestS[i] = s; bestC[i] = c; }
            }
        }
    }

#pragma unroll
    for (int i = 0; i < 8; i++) {
        unsigned long long key =
            ((unsigned long long)fkey(bestS[i]) << 32) | (unsigned int)bestC[i];
        for (int m = 16; m >= 1; m >>= 1) {
            unsigned long long o = __shfl_xor(key, m, 64);
            if (o < key) key = o;
        }
        if (tx == 0) atomicMin(&keys[rowBase + ty * 8 + i], key);
    }
}

// ---------- scatter: quantize gather, ind write, counts, 0.2*x into avg ----------
__global__ __launch_bounds__(256) void scatter_kernel(const float* __restrict__ x,
                                                      const float* __restrict__ embed,
                                                      const unsigned long long* __restrict__ keys,
                                                      float* __restrict__ quant,
                                                      float* __restrict__ ind_out,
                                                      float* __restrict__ counts,
                                                      float* __restrict__ avg_out) {
    int i = blockIdx.x * 256 + threadIdx.x;
    int row = i >> 6;
    int c4  = (i & 63) * 4;
    int idx = (int)(keys[row] & 0xFFFFFFFFull);
    float4 e = *(const float4*)&embed[idx * DIM + c4];
    *(float4*)&quant[row * DIM + c4] = e;
    float4 xv = *(const float4*)&x[row * DIM + c4];
    atomicAdd(&avg_out[idx * DIM + c4 + 0], OMD_F * xv.x);
    atomicAdd(&avg_out[idx * DIM + c4 + 1], OMD_F * xv.y);
    atomicAdd(&avg_out[idx * DIM + c4 + 2], OMD_F * xv.z);
    atomicAdd(&avg_out[idx * DIM + c4 + 3], OMD_F * xv.w);
    if ((i & 63) == 0) {
        ind_out[row] = (float)idx;
        atomicAdd(&counts[idx], 1.0f);
    }
}

// ---------- cluster_size_new + total sum ----------
__global__ __launch_bounds__(256) void csn_kernel(const float* __restrict__ cluster_size,
                                                  const float* __restrict__ counts,
                                                  float* __restrict__ csn_out,
                                                  float* __restrict__ total) {
    int c = blockIdx.x * 256 + threadIdx.x;
    float v = DECAY_F * cluster_size[c] + OMD_F * counts[c];
    csn_out[c] = v;
    float s = v;
    for (int m = 32; m >= 1; m >>= 1) s += __shfl_xor(s, m, 64);
    __shared__ float ws4[4];
    if ((threadIdx.x & 63) == 0) ws4[threadIdx.x >> 6] = s;
    __syncthreads();
    if (threadIdx.x == 0) atomicAdd(total, ws4[0] + ws4[1] + ws4[2] + ws4[3]);
}

// ---------- embed_normalized = avg_new / cs ----------
__global__ __launch_bounds__(256) void norm_kernel(const float* __restrict__ avg_new,
                                                   const float* __restrict__ csn,
                                                   const float* __restrict__ total,
                                                   float* __restrict__ out) {
    int i = blockIdx.x * 256 + threadIdx.x;
    int c = i >> 6;
    float tot = *total;
    float smoothed = (csn[c] + EPS_F) / (tot + (float)CBOOK * EPS_F);
    float cs = smoothed * tot;
    float4 v = ((const float4*)avg_new)[i];
    v.x = v.x / cs; v.y = v.y / cs; v.z = v.z / cs; v.w = v.w / cs;
    ((float4*)out)[i] = v;
}

extern "C" void kernel_launch(void* const* d_in, const int* in_sizes, int n_in,
                              void* d_out, int out_size, void* d_ws, size_t ws_size,
                              hipStream_t stream) {
    const float* x            = (const float*)d_in[0];
    const float* embed        = (const float*)d_in[1];
    const float* cluster_size = (const float*)d_in[2];
    const float* embed_avg    = (const float*)d_in[3];
    float* out = (float*)d_out;
    char*  ws  = (char*)d_ws;

    unsigned long long* keys = (unsigned long long*)(ws + WS_KEYS);
    float* enorm  = (float*)(ws + WS_ENORM);
    float* counts = (float*)(ws + WS_COUNTS);
    float* total  = (float*)(ws + WS_TOTAL);

    hipMemsetAsync(ws + WS_KEYS, 0xFF, NROWS * 8, stream);
    hipMemsetAsync(ws + WS_COUNTS, 0, CBOOK * 4 + 4, stream);

    enorm_kernel<<<CBOOK / 4, 256, 0, stream>>>(embed, enorm);
    init_avg_kernel<<<(CBOOK * DIM / 4) / 256, 256, 0, stream>>>(embed_avg, out + O_AVG);

    if (ws_size >= (size_t)WS_NEED) {
        unsigned short* xsplit = (unsigned short*)(ws + WS_XSPLIT);
        unsigned short* esplit = (unsigned short*)(ws + WS_ESPLIT_OFF);
        split_kernel<<<(NROWS * DIM / 4) / 256, 256, 0, stream>>>(x, xsplit, 0);
        split_kernel<<<(CBOOK * DIM / 4) / 256, 256, 0, stream>>>(embed, esplit, 1);
        dim3 grid(CBOOK / 128, NROWS / 128);
        mfma_argmin_kernel<<<grid, 256, 0, stream>>>(xsplit, esplit, enorm, keys);
    } else {
        dim3 grid(NROWS / BM, NSPLIT);
        argmin_kernel<<<grid, 256, 0, stream>>>(x, embed, enorm, keys);
    }

    scatter_kernel<<<(NROWS * DIM / 4) / 256, 256, 0, stream>>>(
        x, embed, keys, out + O_QUANT, out + O_IND, counts, out + O_AVG);

    csn_kernel<<<CBOOK / 256, 256, 0, stream>>>(cluster_size, counts, out + O_CSN, total);

    norm_kernel<<<(CBOOK * DIM / 4) / 256, 256, 0, stream>>>(
        out + O_AVG, out + O_CSN, total, out + O_NORM);
}

// Round 3
// 404.835 us; speedup vs baseline: 2.2947x; 1.1224x over previous
//
#include <hip/hip_runtime.h>
#include <hip/hip_bf16.h>

#define DECAY_F 0.8f
#define OMD_F   0.2f
#define EPS_F   1e-5f

#define NROWS 16384
#define CBOOK 8192
#define DIM   256
#define KSPLIT 768   // [hi | lo | hi] x [hi | hi | lo]

// ---- ws layout (bytes) ----
#define WS_KEYS   0u            // 16384 * 8
#define WS_ENORM  131072u       // 8192 * 4
#define WS_COUNTS 163840u       // 8192 * 4
#define WS_TOTAL  196608u       // 4
#define WS_XSPLIT 262144u       // 16384*768*2 = 25165824
#define WS_ESPLIT_OFF (262144u + 25165824u)          // 25427968
#define WS_NEED   (WS_ESPLIT_OFF + 12582912u)        // 38010880

// ---- d_out layout (floats) ----
#define O_QUANT 0
#define O_IND   4194304
#define O_NORM  4210688
#define O_CSN   6307840
#define O_AVG   6316032

typedef __attribute__((ext_vector_type(8))) short short8;
typedef __attribute__((ext_vector_type(4))) float f32x4;
typedef __attribute__((ext_vector_type(4))) unsigned short us4;

__device__ __forceinline__ unsigned int fkey(float f) {
    unsigned int b = __float_as_uint(f);
    return (b & 0x80000000u) ? ~b : (b | 0x80000000u);
}
__device__ __forceinline__ unsigned short f2bf(float f) {
    unsigned int u = __float_as_uint(f);
    unsigned int r = (u + 0x7FFFu + ((u >> 16) & 1u)) >> 16;
    return (unsigned short)r;
}
__device__ __forceinline__ float bf2f(unsigned short h) {
    return __uint_as_float(((unsigned int)h) << 16);
}

#define GLOAD_LDS16(g, l) \
    __builtin_amdgcn_global_load_lds((const __attribute__((address_space(1))) void*)(g), \
                                     (__attribute__((address_space(3))) void*)(l), 16, 0, 0)

// ---------- init embed_avg_new = 0.8*embed_avg ----------
__global__ __launch_bounds__(256) void init_avg_kernel(const float* __restrict__ embed_avg,
                                                       float* __restrict__ avg_out) {
    int i = blockIdx.x * 256 + threadIdx.x;
    float4 v = ((const float4*)embed_avg)[i];
    v.x *= DECAY_F; v.y *= DECAY_F; v.z *= DECAY_F; v.w *= DECAY_F;
    ((float4*)avg_out)[i] = v;
}

// ---------- x split: [hi, lo, hi], elementwise ----------
__global__ __launch_bounds__(256) void xsplit_kernel(const float* __restrict__ src,
                                                     unsigned short* __restrict__ dst) {
    int i = blockIdx.x * 256 + threadIdx.x;      // float4 index
    int e4  = i * 4;
    int row = e4 >> 8;
    int k   = e4 & 255;
    float4 v = ((const float4*)src)[i];
    us4 hi, lo;
    hi.x = f2bf(v.x); lo.x = f2bf(v.x - bf2f(hi.x));
    hi.y = f2bf(v.y); lo.y = f2bf(v.y - bf2f(hi.y));
    hi.z = f2bf(v.z); lo.z = f2bf(v.z - bf2f(hi.z));
    hi.w = f2bf(v.w); lo.w = f2bf(v.w - bf2f(hi.w));
    unsigned short* base = dst + (size_t)row * KSPLIT + k;
    *(us4*)(base + 0)   = hi;
    *(us4*)(base + 256) = lo;
    *(us4*)(base + 512) = hi;
}

// ---------- e split [hi, hi, lo] + fused ||e||^2 (one wave per row) ----------
__global__ __launch_bounds__(256) void esplit_kernel(const float* __restrict__ embed,
                                                     unsigned short* __restrict__ dst,
                                                     float* __restrict__ enorm) {
    int row  = (blockIdx.x * 256 + threadIdx.x) >> 6;
    int lane = threadIdx.x & 63;
    float4 v = *(const float4*)&embed[row * DIM + lane * 4];
    float s = v.x * v.x + v.y * v.y + v.z * v.z + v.w * v.w;
    for (int m = 32; m >= 1; m >>= 1) s += __shfl_xor(s, m, 64);
    if (lane == 0) enorm[row] = s;
    us4 hi, lo;
    hi.x = f2bf(v.x); lo.x = f2bf(v.x - bf2f(hi.x));
    hi.y = f2bf(v.y); lo.y = f2bf(v.y - bf2f(hi.y));
    hi.z = f2bf(v.z); lo.z = f2bf(v.z - bf2f(hi.z));
    hi.w = f2bf(v.w); lo.w = f2bf(v.w - bf2f(hi.w));
    unsigned short* base = dst + (size_t)row * KSPLIT + lane * 4;
    *(us4*)(base + 0)   = hi;
    *(us4*)(base + 256) = hi;
    *(us4*)(base + 512) = lo;
}

// ---------- fused bf16 MFMA GEMM (K=768) + per-row argmin ----------
// 128x128 tile, 4 waves (2x2), 2-phase double-buffered pipeline (T3 minimum
// recipe), LDS chunk-XOR swizzle via pre-swizzled global source (rule #21).
__global__ __launch_bounds__(256, 4) void mfma_argmin_kernel(const unsigned short* __restrict__ A,
                                                             const unsigned short* __restrict__ B,
                                                             const float* __restrict__ enorm,
                                                             unsigned long long* __restrict__ keys) {
    __shared__ __align__(16) unsigned short Al[2][128 * 32];
    __shared__ __align__(16) unsigned short Bl[2][128 * 32];

    const int tid  = threadIdx.x;
    const int lane = tid & 63;
    const int wid  = tid >> 6;
    const int wr = wid >> 1, wc = wid & 1;
    const int mBase = blockIdx.y * 128;
    const int nBase = blockIdx.x * 128;

    const int lr = lane & 15;          // A-row / B-col within frag
    const int hk = lane >> 4;          // k-slot 0..3 (logical chunk)

    f32x4 acc[4][4];
#pragma unroll
    for (int i = 0; i < 4; i++)
#pragma unroll
        for (int n = 0; n < 4; n++) acc[i][n] = (f32x4)0.f;

    // ---- staging addresses: LDS dest linear (tid*16B); global source chunk
    // pre-swizzled: physical chunk p = tid&3 holds logical chunk p ^ ((r>>1)&3).
    const int r0 = tid >> 2;
    const int ck = (((tid & 3) ^ ((r0 >> 1) & 3)) << 3);   // element offset in row
    const unsigned short* gA0 = A + (size_t)(mBase + r0) * KSPLIT + ck;
    const unsigned short* gA1 = gA0 + (size_t)64 * KSPLIT;   // (r0+64): same swizzle bits
    const unsigned short* gB0 = B + (size_t)(nBase + r0) * KSPLIT + ck;
    const unsigned short* gB1 = gB0 + (size_t)64 * KSPLIT;

#define STAGE(b, kk) do { \
    GLOAD_LDS16(gA0 + (kk), &Al[b][tid * 8]); \
    GLOAD_LDS16(gA1 + (kk), &Al[b][(tid + 256) * 8]); \
    GLOAD_LDS16(gB0 + (kk), &Bl[b][tid * 8]); \
    GLOAD_LDS16(gB1 + (kk), &Bl[b][(tid + 256) * 8]); \
} while (0)

    // ---- read offsets (swizzled): row R, logical chunk hk -> physical
    // chunk hk ^ ((R>>1)&3); (R>>1)&3 == (lr>>1)&3 for our R forms.
    const int co = ((hk ^ ((lr >> 1) & 3)) << 3);
    int aoff[4], boff[4];
#pragma unroll
    for (int i = 0; i < 4; i++) {
        aoff[i] = (wr * 64 + i * 16 + lr) * 32 + co;
        boff[i] = (wc * 64 + i * 16 + lr) * 32 + co;
    }

    STAGE(0, 0);
    __syncthreads();   // compiler drains vmcnt before s_barrier -> buf0 ready

#pragma unroll 2
    for (int t = 0; t < 24; ++t) {
        const int cur = t & 1;
        if (t < 23) STAGE(cur ^ 1, (t + 1) * 32);   // issue-early: in flight across MFMA

        short8 af[4], bf4[4];
#pragma unroll
        for (int i = 0; i < 4; i++) af[i]  = *(const short8*)&Al[cur][aoff[i]];
#pragma unroll
        for (int n = 0; n < 4; n++) bf4[n] = *(const short8*)&Bl[cur][boff[n]];
#pragma unroll
        for (int i = 0; i < 4; i++)
#pragma unroll
            for (int n = 0; n < 4; n++)
                acc[i][n] = __builtin_amdgcn_mfma_f32_16x16x32_bf16(af[i], bf4[n], acc[i][n], 0, 0, 0);

        __syncthreads();   // drain: next-tile loads landed; reads of cur done
    }
#undef STAGE

    // epilogue: score = ||e||^2 - 2*dot; argmin per row
    float en4[4];
    int   c4[4];
#pragma unroll
    for (int n = 0; n < 4; n++) {
        c4[n]  = nBase + wc * 64 + n * 16 + lr;
        en4[n] = enorm[c4[n]];
    }
#pragma unroll
    for (int i = 0; i < 4; i++) {
#pragma unroll
        for (int reg = 0; reg < 4; reg++) {
            float bs = 3.4e38f; int bc = 0;
#pragma unroll
            for (int n = 0; n < 4; n++) {
                float s = en4[n] - 2.f * acc[i][n][reg];
                if (s < bs || (s == bs && c4[n] < bc)) { bs = s; bc = c4[n]; }
            }
            unsigned long long key =
                ((unsigned long long)fkey(bs) << 32) | (unsigned int)bc;
#pragma unroll
            for (int m = 8; m >= 1; m >>= 1) {
                unsigned long long o = __shfl_xor(key, m, 64);
                if (o < key) key = o;
            }
            if (lr == 0)
                atomicMin(&keys[mBase + wr * 64 + i * 16 + hk * 4 + reg], key);
        }
    }
}

// ---------- fallback fp32 fused GEMM+argmin ----------
#define BM 64
#define BN 256
#define KB 16
#define NSPLIT 4

__global__ __launch_bounds__(256) void argmin_kernel(const float* __restrict__ x,
                                                     const float* __restrict__ embed,
                                                     const float* __restrict__ enorm,
                                                     unsigned long long* __restrict__ keys) {
    __shared__ float xs[KB][BM];
    __shared__ float es[KB][BN];

    const int tid = threadIdx.x;
    const int tx = tid & 31;
    const int ty = tid >> 5;
    const int rowBase = blockIdx.x * BM;
    const int cStart = blockIdx.y * (CBOOK / NSPLIT);

    float bestS[8];
    int   bestC[8];
#pragma unroll
    for (int i = 0; i < 8; i++) { bestS[i] = 3.4e38f; bestC[i] = 0; }

    float acc[8][8];

    for (int cb = 0; cb < CBOOK / NSPLIT; cb += BN) {
        const int cbase = cStart + cb;
#pragma unroll
        for (int i = 0; i < 8; i++)
#pragma unroll
            for (int j = 0; j < 8; j++) acc[i][j] = 0.f;

        for (int kk = 0; kk < DIM; kk += KB) {
            __syncthreads();
            {
                int r  = tid >> 2;
                int k4 = (tid & 3) * 4;
                float4 v = *(const float4*)&x[(rowBase + r) * DIM + kk + k4];
                xs[k4 + 0][r] = v.x; xs[k4 + 1][r] = v.y;
                xs[k4 + 2][r] = v.z; xs[k4 + 3][r] = v.w;
            }
            {
                const float4* src = (const float4*)&embed[(cbase + tid) * DIM + kk];
#pragma unroll
                for (int q = 0; q < 4; q++) {
                    float4 v = src[q];
                    es[q * 4 + 0][tid] = v.x; es[q * 4 + 1][tid] = v.y;
                    es[q * 4 + 2][tid] = v.z; es[q * 4 + 3][tid] = v.w;
                }
            }
            __syncthreads();
#pragma unroll
            for (int k = 0; k < KB; k++) {
                float xr[8], er[8];
                *(float4*)&xr[0] = *(const float4*)&xs[k][ty * 8];
                *(float4*)&xr[4] = *(const float4*)&xs[k][ty * 8 + 4];
                *(float4*)&er[0] = *(const float4*)&es[k][tx * 4];
                *(float4*)&er[4] = *(const float4*)&es[k][128 + tx * 4];
#pragma unroll
                for (int i = 0; i < 8; i++)
#pragma unroll
                    for (int j = 0; j < 8; j++)
                        acc[i][j] = fmaf(xr[i], er[j], acc[i][j]);
            }
        }
#pragma unroll
        for (int j = 0; j < 8; j++) {
            int c = cbase + ((j < 4) ? (tx * 4 + j) : (128 + tx * 4 + (j - 4)));
            float en = enorm[c];
#pragma unroll
            for (int i = 0; i < 8; i++) {
                float s = en - 2.f * acc[i][j];
                if (s < bestS[i]) { bestS[i] = s; bestC[i] = c; }
            }
        }
    }

#pragma unroll
    for (int i = 0; i < 8; i++) {
        unsigned long long key =
            ((unsigned long long)fkey(bestS[i]) << 32) | (unsigned int)bestC[i];
        for (int m = 16; m >= 1; m >>= 1) {
            unsigned long long o = __shfl_xor(key, m, 64);
            if (o < key) key = o;
        }
        if (tx == 0) atomicMin(&keys[rowBase + ty * 8 + i], key);
    }
}

// ---------- scatter: quantize gather, ind write, counts, 0.2*x into avg ----------
__global__ __launch_bounds__(256) void scatter_kernel(const float* __restrict__ x,
                                                      const float* __restrict__ embed,
                                                      const unsigned long long* __restrict__ keys,
                                                      float* __restrict__ quant,
                                                      float* __restrict__ ind_out,
                                                      float* __restrict__ counts,
                                                      float* __restrict__ avg_out) {
    int i = blockIdx.x * 256 + threadIdx.x;
    int row = i >> 6;
    int c4  = (i & 63) * 4;
    int idx = (int)(keys[row] & 0xFFFFFFFFull);
    float4 e = *(const float4*)&embed[idx * DIM + c4];
    *(float4*)&quant[row * DIM + c4] = e;
    float4 xv = *(const float4*)&x[row * DIM + c4];
    atomicAdd(&avg_out[idx * DIM + c4 + 0], OMD_F * xv.x);
    atomicAdd(&avg_out[idx * DIM + c4 + 1], OMD_F * xv.y);
    atomicAdd(&avg_out[idx * DIM + c4 + 2], OMD_F * xv.z);
    atomicAdd(&avg_out[idx * DIM + c4 + 3], OMD_F * xv.w);
    if ((i & 63) == 0) {
        ind_out[row] = (float)idx;
        atomicAdd(&counts[idx], 1.0f);
    }
}

// ---------- cluster_size_new + total sum ----------
__global__ __launch_bounds__(256) void csn_kernel(const float* __restrict__ cluster_size,
                                                  const float* __restrict__ counts,
                                                  float* __restrict__ csn_out,
                                                  float* __restrict__ total) {
    int c = blockIdx.x * 256 + threadIdx.x;
    float v = DECAY_F * cluster_size[c] + OMD_F * counts[c];
    csn_out[c] = v;
    float s = v;
    for (int m = 32; m >= 1; m >>= 1) s += __shfl_xor(s, m, 64);
    __shared__ float ws4[4];
    if ((threadIdx.x & 63) == 0) ws4[threadIdx.x >> 6] = s;
    __syncthreads();
    if (threadIdx.x == 0) atomicAdd(total, ws4[0] + ws4[1] + ws4[2] + ws4[3]);
}

// ---------- embed_normalized = avg_new / cs ----------
__global__ __launch_bounds__(256) void norm_kernel(const float* __restrict__ avg_new,
                                                   const float* __restrict__ csn,
                                                   const float* __restrict__ total,
                                                   float* __restrict__ out) {
    int i = blockIdx.x * 256 + threadIdx.x;
    int c = i >> 6;
    float tot = *total;
    float smoothed = (csn[c] + EPS_F) / (tot + (float)CBOOK * EPS_F);
    float cs = smoothed * tot;
    float4 v = ((const float4*)avg_new)[i];
    v.x = v.x / cs; v.y = v.y / cs; v.z = v.z / cs; v.w = v.w / cs;
    ((float4*)out)[i] = v;
}

extern "C" void kernel_launch(void* const* d_in, const int* in_sizes, int n_in,
                              void* d_out, int out_size, void* d_ws, size_t ws_size,
                              hipStream_t stream) {
    const float* x            = (const float*)d_in[0];
    const float* embed        = (const float*)d_in[1];
    const float* cluster_size = (const float*)d_in[2];
    const float* embed_avg    = (const float*)d_in[3];
    float* out = (float*)d_out;
    char*  ws  = (char*)d_ws;

    unsigned long long* keys = (unsigned long long*)(ws + WS_KEYS);
    float* enorm  = (float*)(ws + WS_ENORM);
    float* counts = (float*)(ws + WS_COUNTS);
    float* total  = (float*)(ws + WS_TOTAL);

    hipMemsetAsync(ws + WS_KEYS, 0xFF, NROWS * 8, stream);
    hipMemsetAsync(ws + WS_COUNTS, 0, CBOOK * 4 + 4, stream);

    init_avg_kernel<<<(CBOOK * DIM / 4) / 256, 256, 0, stream>>>(embed_avg, out + O_AVG);

    if (ws_size >= (size_t)WS_NEED) {
        unsigned short* xsplit = (unsigned short*)(ws + WS_XSPLIT);
        unsigned short* esplit = (unsigned short*)(ws + WS_ESPLIT_OFF);
        xsplit_kernel<<<(NROWS * DIM / 4) / 256, 256, 0, stream>>>(x, xsplit);
        esplit_kernel<<<CBOOK / 4, 256, 0, stream>>>(embed, esplit, enorm);
        dim3 grid(CBOOK / 128, NROWS / 128);
        mfma_argmin_kernel<<<grid, 256, 0, stream>>>(xsplit, esplit, enorm, keys);
    } else {
        // fp32 fallback needs enorm too
        esplit_kernel<<<CBOOK / 4, 256, 0, stream>>>(embed, (unsigned short*)(ws + WS_XSPLIT), enorm);
        dim3 grid(NROWS / BM, NSPLIT);
        argmin_kernel<<<grid, 256, 0, stream>>>(x, embed, enorm, keys);
    }

    scatter_kernel<<<(NROWS * DIM / 4) / 256, 256, 0, stream>>>(
        x, embed, keys, out + O_QUANT, out + O_IND, counts, out + O_AVG);

    csn_kernel<<<CBOOK / 256, 256, 0, stream>>>(cluster_size, counts, out + O_CSN, total);

    norm_kernel<<<(CBOOK * DIM / 4) / 256, 256, 0, stream>>>(
        out + O_AVG, out + O_CSN, total, out + O_NORM);
}